// Round 9
// baseline (489.868 us; speedup 1.0000x reference)
//
#include <hip/hip_runtime.h>
#include <hip/hip_fp16.h>

#define D   128
#define NN  40000
#define NB  625      // dst buckets per relation (64 nodes each)
#define GH  64       // histogram slices per relation (partition, no overlap)
#define GF  128      // fill slices (= fill grid per relation)

typedef unsigned long long ull;

struct Ptrs { const int* src[4]; const int* dst[4]; const float* w[4]; };

// ---- convert f32 table -> fp16, SPLIT column-half layout -------------------
// out[half][node][c] ; half = col/64. Each thread converts 8 consecutive cols.
__global__ __launch_bounds__(256) void conv_kernel(
    const float* __restrict__ in, __half* __restrict__ out, int n8)
{
    int i = blockIdx.x * 256 + threadIdx.x;
    if (i >= n8) return;
    int node = i >> 4;            // 16 chunks of 8 per row
    int j    = i & 15;
    int col0 = j * 8;
    const float4* a = (const float4*)(in + (size_t)node * D + col0);
    float4 v0 = a[0], v1 = a[1];
    __half2 pack[4];
    pack[0] = __floats2half2_rn(v0.x, v0.y);
    pack[1] = __floats2half2_rn(v0.z, v0.w);
    pack[2] = __floats2half2_rn(v1.x, v1.y);
    pack[3] = __floats2half2_rn(v1.z, v1.w);
    int half = col0 >> 6;
    __half* op = out + (size_t)half * NN * 64 + (size_t)node * 64 + (col0 & 63);
    *(float4*)op = *(float4*)pack;
}

// ---- weighted out-degree: FULL-table LDS histogram (156.25 KB) -------------
__global__ __launch_bounds__(1024) void hist_kernel(
    Ptrs p, __half* __restrict__ histo16, int E)
{
    __shared__ float hist[NN];          // 156.25 KB -> 1 block/CU, 16 waves
    const int bx  = blockIdx.x;         // rel*GH + rep
    const int rel = bx >> 6;
    const int rep = bx & (GH - 1);
    const int tid = threadIdx.x;

    for (int i = tid; i < NN; i += 1024) hist[i] = 0.f;
    __syncthreads();

    const int es  = (E + GH - 1) / GH;
    const int beg = rep * es;
    const int end = min(beg + es, E);
    const int* idx = p.src[rel];
    const float* w = p.w[rel];
    for (int e = beg + tid; e < end; e += 1024)
        atomicAdd(&hist[idx[e]], w[e]);
    __syncthreads();

    __half2* outp = (__half2*)(histo16 + (size_t)bx * NN);
    for (int i = tid; i < NN / 2; i += 1024)
        outp[i] = __floats2half2_rn(hist[2 * i], hist[2 * i + 1]);
}

// ---- reduce fp16 replicas -> rdego[rel][node] = rsqrt(out-degree) ----------
__global__ __launch_bounds__(256) void reduce_kernel(
    const __half* __restrict__ histo16, float* __restrict__ rdego, int total)
{
    int i = blockIdx.x * 256 + threadIdx.x;     // i = rel*NN + node
    if (i >= total) return;
    int rel = i / NN;
    int node = i - rel * NN;
    const __half* bp = histo16 + (size_t)rel * GH * NN + node;
    float v = 0.f;
#pragma unroll
    for (int r = 0; r < GH; ++r) v += __half2float(bp[(size_t)r * NN]);
    rdego[i] = rsqrtf(v);
}

// ---- per-(rel,slice) coarse bucket counts in tiny LDS ----------------------
__global__ __launch_bounds__(256) void bcnt_kernel(
    Ptrs p, int* __restrict__ cnt_store, int E)
{
    __shared__ int cnt[NB];
    const int rel = blockIdx.x / GF;
    const int rep = blockIdx.x - rel * GF;
    const int tid = threadIdx.x;
    for (int b = tid; b < NB; b += 256) cnt[b] = 0;
    __syncthreads();
    const int es  = (E + GF - 1) / GF;
    const int beg = rep * es;
    const int end = min(beg + es, E);
    const int* dst = p.dst[rel];
    for (int e = beg + tid; e < end; e += 256)
        atomicAdd(&cnt[dst[e] >> 6], 1);
    __syncthreads();
    for (int b = tid; b < NB; b += 256)
        cnt_store[((size_t)(rel * NB + b)) * GF + rep] = cnt[b];
}

// ---- 3-kernel scan over 4*NB*GF = 320000 counts ----------------------------
__device__ inline int block_excl_scan(int v, int tid) {
    __shared__ int wsum[16];
    int lane = tid & 63, wid = tid >> 6;
    int x = v;
#pragma unroll
    for (int off = 1; off < 64; off <<= 1) {
        int y = __shfl_up(x, off, 64);
        if (lane >= off) x += y;
    }
    if (lane == 63) wsum[wid] = x;
    __syncthreads();
    if (wid == 0) {
        int y = (lane < 16) ? wsum[lane] : 0;
#pragma unroll
        for (int off = 1; off < 16; off <<= 1) {
            int t = __shfl_up(y, off, 64);
            if (lane >= off) y += t;
        }
        if (lane < 16) wsum[lane] = y;
    }
    __syncthreads();
    int woff = wid ? wsum[wid - 1] : 0;
    return woff + x - v;
}

__global__ __launch_bounds__(1024) void scan1_kernel(
    const int* __restrict__ cnt_store, int* __restrict__ scanex,
    int* __restrict__ bsum, int total)
{
    int tid = threadIdx.x;
    int i = blockIdx.x * 1024 + tid;
    int v = (i < total) ? cnt_store[i] : 0;
    int excl = block_excl_scan(v, tid);
    if (i < total) scanex[i] = excl;
    if (tid == 1023) bsum[blockIdx.x] = excl + v;
}

__global__ __launch_bounds__(1024) void scan2_kernel(int* __restrict__ bsum, int nb)
{
    int tid = threadIdx.x;
    int v = (tid < nb) ? bsum[tid] : 0;
    int excl = block_excl_scan(v, tid);
    if (tid < nb) bsum[tid] = excl;
}

__global__ __launch_bounds__(256) void scan3_kernel(
    const int* __restrict__ scanex, const int* __restrict__ bsum,
    int* __restrict__ cursor_base, int* __restrict__ bucket_ptr,
    int total, int E)
{
    int i = blockIdx.x * 256 + threadIdx.x;
    if (i >= total) return;
    int v = scanex[i] + bsum[i >> 10];
    int rel = i / (NB * GF);
    int rem = i - rel * (NB * GF);
    int b = rem / GF, rep = rem - b * GF;
    int local = v - rel * E;            // each relation has exactly E edges
    cursor_base[i] = local;
    if (rep == 0) bucket_ptr[rel * (NB + 1) + b] = local;
    if (rem == 0) bucket_ptr[rel * (NB + 1) + NB] = E;
}

// ---- fill: coarse bucket sort of (src, dlocal, raw w); LDS cursors ---------
__global__ __launch_bounds__(512) void fill_kernel(
    const int* __restrict__ src, const int* __restrict__ dst,
    const float* __restrict__ w, const int* __restrict__ cursor_base_r,
    ull* __restrict__ csr8, int E)
{
    __shared__ int lcur[NB];
    const int rep = blockIdx.x;
    const int tid = threadIdx.x;
    for (int b = tid; b < NB; b += 512)
        lcur[b] = cursor_base_r[(size_t)b * GF + rep];
    __syncthreads();
    const int es  = (E + GF - 1) / GF;
    const int beg = rep * es;
    const int end = min(beg + es, E);
    for (int e = beg + tid; e < end; e += 512) {
        int s = src[e];
        int d = dst[e];
        int pos = atomicAdd(&lcur[d >> 6], 1);
        ull rec = (ull)(unsigned)(s | ((d & 63) << 16)) |
                  ((ull)__float_as_uint(w[e]) << 32);
        csr8[pos] = rec;
    }
}

// ---- sort2: bucket -> exact per-dst CSR; bake wn; 4B records ---------------
__global__ __launch_bounds__(256) void sort2_kernel(
    const int* __restrict__ bucket_ptr_r, const ull* __restrict__ csr8,
    const float* __restrict__ rdego_r, unsigned* __restrict__ csr2u,
    int* __restrict__ row_ptr_r, int E)
{
    __shared__ int cnt[64];
    __shared__ int cur[64];
    __shared__ float swsum[64];
    const int b = blockIdx.x;
    const int tid = threadIdx.x;
    const int beg = bucket_ptr_r[b];
    const int end = bucket_ptr_r[b + 1];
    if (tid < 64) { cnt[tid] = 0; swsum[tid] = 0.f; }
    __syncthreads();
    for (int e = beg + tid; e < end; e += 256) {
        ull rec = csr8[e];
        int j = (int)((rec >> 16) & 63);
        atomicAdd(&cnt[j], 1);
        atomicAdd(&swsum[j], __uint_as_float((unsigned)(rec >> 32)));
    }
    __syncthreads();
    if (tid < 64) {                      // wave 0: exclusive scan of 64 bins
        int v = cnt[tid];
        int x = v;
#pragma unroll
        for (int off = 1; off < 64; off <<= 1) {
            int y = __shfl_up(x, off, 64);
            if (tid >= off) x += y;
        }
        int start = beg + x - v;
        cur[tid] = start;
        row_ptr_r[b * 64 + tid] = start;
        swsum[tid] = rsqrtf(swsum[tid]);
        if (b == 0 && tid == 0) row_ptr_r[NN] = E;
    }
    __syncthreads();
    for (int e = beg + tid; e < end; e += 256) {
        ull rec = csr8[e];
        int j = (int)((rec >> 16) & 63);
        int s = (int)(rec & 0xFFFF);
        float wn = __uint_as_float((unsigned)(rec >> 32)) * rdego_r[s] * swsum[j];
        int pos = atomicAdd(&cur[j], 1);
        csr2u[pos] = (unsigned)s |
                     ((unsigned)__half_as_ushort(__float2half_rn(wn)) << 16);
    }
}

// ---- gather: one wave/node; COLUMN-HALF pass; 8 edges x 8 lanes x 16B ------
// h16half = [NN][64] fp16 table for this pass (5.12 MB -> fits XCD L2-ish)
__global__ __launch_bounds__(256) void gather16_kernel(
    const int* __restrict__ row_ptr_r, const unsigned* __restrict__ csr2u,
    const __half* __restrict__ h16half, __half* __restrict__ agg16,
    int colbase, int n)
{
    int node = (blockIdx.x * 256 + threadIdx.x) >> 6;
    int lane = threadIdx.x & 63;
    if (node >= n) return;
    int beg = row_ptr_r[node], end = row_ptr_r[node + 1];
    const int g = lane >> 3, l8 = lane & 7;   // 8 groups x 8 lanes

    float acc[8] = {};
    for (int e = beg; e < end; e += 8) {
        int ee = e + g;
        int valid = ee < end;
        unsigned rec = csr2u[valid ? ee : (end - 1)];
        int s = (int)(rec & 0xFFFF);
        float wn = valid ? __half2float(__ushort_as_half((unsigned short)(rec >> 16))) : 0.f;
        float4 hv4 = ((const float4*)(h16half + (size_t)s * 64))[l8];
        __half2* hp = (__half2*)&hv4;
        float2 f0 = __half22float2(hp[0]);
        float2 f1 = __half22float2(hp[1]);
        float2 f2 = __half22float2(hp[2]);
        float2 f3 = __half22float2(hp[3]);
        acc[0] += wn * f0.x; acc[1] += wn * f0.y;
        acc[2] += wn * f1.x; acc[3] += wn * f1.y;
        acc[4] += wn * f2.x; acc[5] += wn * f2.y;
        acc[6] += wn * f3.x; acc[7] += wn * f3.y;
    }
#pragma unroll
    for (int k = 0; k < 8; ++k) {
        acc[k] += __shfl_xor(acc[k], 8, 64);
        acc[k] += __shfl_xor(acc[k], 16, 64);
        acc[k] += __shfl_xor(acc[k], 32, 64);
    }
    if (g == 0) {
        __half2 pack[4];
        pack[0] = __floats2half2_rn(acc[0], acc[1]);
        pack[1] = __floats2half2_rn(acc[2], acc[3]);
        pack[2] = __floats2half2_rn(acc[4], acc[5]);
        pack[3] = __floats2half2_rn(acc[6], acc[7]);
        ((float4*)(agg16 + (size_t)node * D + colbase))[l8] = *(float4*)pack;
    }
}

// ---- proj: agg16 @ W, fused bias+ReLU+0.5*merge ----------------------------
__global__ __launch_bounds__(256) void proj_fused_kernel(
    const __half* __restrict__ agg16, const float* __restrict__ W,
    const float* __restrict__ b, float* __restrict__ out, int add)
{
    __shared__ float Ws[64 * D];
    __shared__ float Hs[32 * D];
    const int t = threadIdx.x;
    const int row0 = blockIdx.x * 32;

    // stage 32x128 fp16 rows, convert to f32 in LDS
    const float4* A4 = (const float4*)(agg16 + (size_t)row0 * D);
    for (int i = t; i < 512; i += 256) {
        float4 v = A4[i];
        __half2* hp = (__half2*)&v;
        float2 f0 = __half22float2(hp[0]);
        float2 f1 = __half22float2(hp[1]);
        float2 f2 = __half22float2(hp[2]);
        float2 f3 = __half22float2(hp[3]);
        *(float4*)&Hs[i * 8]     = make_float4(f0.x, f0.y, f1.x, f1.y);
        *(float4*)&Hs[i * 8 + 4] = make_float4(f2.x, f2.y, f3.x, f3.y);
    }

    const int c0 = (t & 31) * 4;
    const int r0 = (t >> 5) * 4;
    float acc[4][4] = {};

    for (int kc = 0; kc < 2; ++kc) {
        __syncthreads();
        const float4* W4 = (const float4*)(W + (size_t)kc * 64 * D);
        float4* Ws4 = (float4*)Ws;
#pragma unroll
        for (int i = 0; i < 8; ++i) Ws4[t + 256 * i] = W4[t + 256 * i];
        __syncthreads();

        for (int k = 0; k < 64; ++k) {
            float4 wv = *(const float4*)&Ws[k * D + c0];
            float h0 = Hs[(r0 + 0) * D + kc * 64 + k];
            float h1 = Hs[(r0 + 1) * D + kc * 64 + k];
            float h2 = Hs[(r0 + 2) * D + kc * 64 + k];
            float h3 = Hs[(r0 + 3) * D + kc * 64 + k];
            acc[0][0] += h0 * wv.x; acc[0][1] += h0 * wv.y; acc[0][2] += h0 * wv.z; acc[0][3] += h0 * wv.w;
            acc[1][0] += h1 * wv.x; acc[1][1] += h1 * wv.y; acc[1][2] += h1 * wv.z; acc[1][3] += h1 * wv.w;
            acc[2][0] += h2 * wv.x; acc[2][1] += h2 * wv.y; acc[2][2] += h2 * wv.z; acc[2][3] += h2 * wv.w;
            acc[3][0] += h3 * wv.x; acc[3][1] += h3 * wv.y; acc[3][2] += h3 * wv.z; acc[3][3] += h3 * wv.w;
        }
    }

    float4 bv = *(const float4*)&b[c0];
#pragma unroll
    for (int r = 0; r < 4; ++r) {
        float* op = &out[(size_t)(row0 + r0 + r) * D + c0];
        float4 v;
        v.x = 0.5f * fmaxf(acc[r][0] + bv.x, 0.0f);
        v.y = 0.5f * fmaxf(acc[r][1] + bv.y, 0.0f);
        v.z = 0.5f * fmaxf(acc[r][2] + bv.z, 0.0f);
        v.w = 0.5f * fmaxf(acc[r][3] + bv.w, 0.0f);
        if (add) {
            float4 o = *(const float4*)op;
            v.x += o.x; v.y += o.y; v.z += o.z; v.w += o.w;
        }
        *(float4*)op = v;
    }
}

extern "C" void kernel_launch(void* const* d_in, const int* in_sizes, int n_in,
                              void* d_out, int out_size, void* d_ws, size_t ws_size,
                              hipStream_t stream) {
    const float* com_emb = (const float*)d_in[0];
    const float* pos_emb = (const float*)d_in[1];
    const int E = in_sizes[2];       // 1,000,000
    const int N = NN;

    float* out = (float*)d_out;
    float* out_com = out;
    float* out_pos = out + (size_t)N * D;

    // relation order: 0=cflow(com->com) 1=supply(pos->com) 2=pflow(pos->pos) 3=demand(com->pos)
    Ptrs ptrs;
    ptrs.src[0] = (const int*)d_in[8];  ptrs.dst[0] = (const int*)d_in[9];  ptrs.w[0] = (const float*)d_in[10];
    ptrs.src[1] = (const int*)d_in[5];  ptrs.dst[1] = (const int*)d_in[6];  ptrs.w[1] = (const float*)d_in[7];
    ptrs.src[2] = (const int*)d_in[11]; ptrs.dst[2] = (const int*)d_in[12]; ptrs.w[2] = (const float*)d_in[13];
    ptrs.src[3] = (const int*)d_in[2];  ptrs.dst[3] = (const int*)d_in[3];  ptrs.w[3] = (const float*)d_in[4];

    // ws layout (~38 MB). histo16 (20.48 MB, dead after reduce) overlays
    // csr8+csr2u+h16 (22.24 MB) — all written only after reduce completes.
    const int totalCnt = 4 * NB * GF;           // 320000
    char* p = (char*)d_ws;
    float* rdego       = (float*)p;  p += (size_t)4 * N * 4;              // 0.64 MB
    int*   cnt_store   = (int*)p;    p += (size_t)totalCnt * 4;           // 1.28 MB
    int*   scanex      = (int*)p;    p += (size_t)totalCnt * 4;           // 1.28 MB
    int*   bsum        = (int*)p;    p += (size_t)1024 * 4;
    int*   cursor_base = (int*)p;    p += (size_t)totalCnt * 4;           // 1.28 MB
    int*   bucket_ptr  = (int*)p;    p += (size_t)4 * (NB + 1) * 4;
    int*   row_ptr     = (int*)p;    p += (size_t)4 * (N + 1) * 4;        // 0.64 MB
    ull*   csr8        = (ull*)p;    p += (size_t)E * 8;                  // 8 MB
    unsigned* csr2u    = (unsigned*)p; p += (size_t)E * 4;                // 4 MB
    __half* h16        = (__half*)p; p += (size_t)N * D * 2;              // 10.24 MB (2 col-half tables)
    __half* agg16      = (__half*)p;                                      // 10.24 MB
    __half* histo16    = (__half*)csr8;                                   // overlay

    hist_kernel<<<4 * GH, 1024, 0, stream>>>(ptrs, histo16, E);
    reduce_kernel<<<(4 * N + 255) / 256, 256, 0, stream>>>(histo16, rdego, 4 * N);
    bcnt_kernel<<<4 * GF, 256, 0, stream>>>(ptrs, cnt_store, E);
    const int sBlocks = (totalCnt + 1023) / 1024;
    scan1_kernel<<<sBlocks, 1024, 0, stream>>>(cnt_store, scanex, bsum, totalCnt);
    scan2_kernel<<<1, 1024, 0, stream>>>(bsum, sBlocks);
    scan3_kernel<<<(totalCnt + 255) / 256, 256, 0, stream>>>(scanex, bsum, cursor_base,
                                                             bucket_ptr, totalCnt, E);

    const int cBlocks = (N * D / 8 + 255) / 256;
    const int gBlocks = N / 4;                 // 1 wave per dst node
    const int pBlocks = N / 32;
    auto run_rel = [&](int rel, const float* W, const float* b,
                       float* oh, int add) {
        int* rp = row_ptr + (size_t)rel * (N + 1);
        fill_kernel<<<GF, 512, 0, stream>>>(ptrs.src[rel], ptrs.dst[rel], ptrs.w[rel],
                                            cursor_base + (size_t)rel * NB * GF, csr8, E);
        sort2_kernel<<<NB, 256, 0, stream>>>(bucket_ptr + (size_t)rel * (NB + 1), csr8,
                                             rdego + (size_t)rel * N, csr2u, rp, E);
        // two temporally-separated column-half passes (XCD-L2-sized working set)
        gather16_kernel<<<gBlocks, 256, 0, stream>>>(rp, csr2u, h16, agg16, 0, N);
        gather16_kernel<<<gBlocks, 256, 0, stream>>>(rp, csr2u, h16 + (size_t)N * 64,
                                                     agg16, 64, N);
        proj_fused_kernel<<<pBlocks, 256, 0, stream>>>(agg16, W, b, oh, add);
    };

    conv_kernel<<<cBlocks, 256, 0, stream>>>(com_emb, h16, N * D / 8);
    run_rel(0, (const float*)d_in[18], (const float*)d_in[19], out_com, 0); // cflow (com)
    conv_kernel<<<cBlocks, 256, 0, stream>>>(pos_emb, h16, N * D / 8);
    run_rel(1, (const float*)d_in[16], (const float*)d_in[17], out_com, 1); // supply (pos)
    run_rel(2, (const float*)d_in[20], (const float*)d_in[21], out_pos, 0); // pflow (pos)
    conv_kernel<<<cBlocks, 256, 0, stream>>>(com_emb, h16, N * D / 8);
    run_rel(3, (const float*)d_in[14], (const float*)d_in[15], out_pos, 1); // demand (com)
}

// Round 11
// 355.077 us; speedup vs baseline: 1.3796x; 1.3796x over previous
//
#include <hip/hip_runtime.h>
#include <hip/hip_fp16.h>

#define D   128
#define NN  40000
#define NB  625      // dst buckets per relation (64 nodes each)
#define GH  64       // histogram slices per relation
#define GF  128      // fill slices per relation

typedef unsigned long long ull;
typedef __attribute__((ext_vector_type(8))) _Float16 f16x8;
typedef __attribute__((ext_vector_type(4))) float f32x4;

struct Ptrs { const int* src[4]; const int* dst[4]; const float* w[4]; };

// ---- convert f32 table -> fp16 interleaved [node][128] ---------------------
__global__ __launch_bounds__(256) void conv_kernel(
    const float* __restrict__ in, __half* __restrict__ out, int n8)
{
    int i = blockIdx.x * 256 + threadIdx.x;
    if (i >= n8) return;
    const float4* a = (const float4*)in + (size_t)i * 2;
    float4 v0 = a[0], v1 = a[1];
    __half2 pack[4];
    pack[0] = __floats2half2_rn(v0.x, v0.y);
    pack[1] = __floats2half2_rn(v0.z, v0.w);
    pack[2] = __floats2half2_rn(v1.x, v1.y);
    pack[3] = __floats2half2_rn(v1.z, v1.w);
    ((float4*)out)[i] = *(float4*)pack;
}

// ---- pack W [128][128] f32 -> per-fragment fp16 [kt(4)][ct(8)][lane(64)][8]
// element j of (kt,ct,lane) = W[kt*32 + (lane>>4)*8 + j][ct*16 + (lane&15)]
__global__ __launch_bounds__(256) void wpack_kernel(
    const float* __restrict__ W0, const float* __restrict__ W1,
    const float* __restrict__ W2, const float* __restrict__ W3,
    __half* __restrict__ wp)
{
    int t = blockIdx.x * 256 + threadIdx.x;   // rel*2048 + idx
    int rel = t >> 11;
    int idx = t & 2047;
    int lane = idx & 63;
    int ct = (idx >> 6) & 7;
    int kt = idx >> 9;
    const float* W = rel == 0 ? W0 : rel == 1 ? W1 : rel == 2 ? W2 : W3;
    int k0 = kt * 32 + (lane >> 4) * 8;
    int col = ct * 16 + (lane & 15);
    __half tmp[8];
#pragma unroll
    for (int j = 0; j < 8; ++j)
        tmp[j] = __float2half_rn(W[(size_t)(k0 + j) * D + col]);
    *(float4*)(wp + (size_t)t * 8) = *(float4*)tmp;
}

// ---- weighted out-degree: FULL-table LDS histogram (156.25 KB) -------------
__global__ __launch_bounds__(1024) void hist_kernel(
    Ptrs p, __half* __restrict__ histo16, int E)
{
    __shared__ float hist[NN];
    const int bx  = blockIdx.x;         // rel*GH + rep
    const int rel = bx >> 6;
    const int rep = bx & (GH - 1);
    const int tid = threadIdx.x;

    for (int i = tid; i < NN; i += 1024) hist[i] = 0.f;
    __syncthreads();

    const int es  = (E + GH - 1) / GH;
    const int beg = rep * es;
    const int end = min(beg + es, E);
    const int* idx = p.src[rel];
    const float* w = p.w[rel];
    for (int e = beg + tid; e < end; e += 1024)
        atomicAdd(&hist[idx[e]], w[e]);
    __syncthreads();

    __half2* outp = (__half2*)(histo16 + (size_t)bx * NN);
    for (int i = tid; i < NN / 2; i += 1024)
        outp[i] = __floats2half2_rn(hist[2 * i], hist[2 * i + 1]);
}

__global__ __launch_bounds__(256) void reduce_kernel(
    const __half* __restrict__ histo16, float* __restrict__ rdego, int total)
{
    int i = blockIdx.x * 256 + threadIdx.x;     // i = rel*NN + node
    if (i >= total) return;
    int rel = i / NN;
    int node = i - rel * NN;
    const __half* bp = histo16 + (size_t)rel * GH * NN + node;
    float v = 0.f;
#pragma unroll
    for (int r = 0; r < GH; ++r) v += __half2float(bp[(size_t)r * NN]);
    rdego[i] = rsqrtf(v);
}

// ---- per-(rel,slice) coarse bucket counts ----------------------------------
__global__ __launch_bounds__(256) void bcnt_kernel(
    Ptrs p, int* __restrict__ cnt_store, int E)
{
    __shared__ int cnt[NB];
    const int rel = blockIdx.x / GF;
    const int rep = blockIdx.x - rel * GF;
    const int tid = threadIdx.x;
    for (int b = tid; b < NB; b += 256) cnt[b] = 0;
    __syncthreads();
    const int es  = (E + GF - 1) / GF;
    const int beg = rep * es;
    const int end = min(beg + es, E);
    const int* dst = p.dst[rel];
    for (int e = beg + tid; e < end; e += 256)
        atomicAdd(&cnt[dst[e] >> 6], 1);
    __syncthreads();
    for (int b = tid; b < NB; b += 256)
        cnt_store[((size_t)(rel * NB + b)) * GF + rep] = cnt[b];
}

// ---- 3-kernel scan over 4*NB*GF = 320000 counts ----------------------------
__device__ inline int block_excl_scan(int v, int tid) {
    __shared__ int wsum[16];
    int lane = tid & 63, wid = tid >> 6;
    int x = v;
#pragma unroll
    for (int off = 1; off < 64; off <<= 1) {
        int y = __shfl_up(x, off, 64);
        if (lane >= off) x += y;
    }
    if (lane == 63) wsum[wid] = x;
    __syncthreads();
    if (wid == 0) {
        int y = (lane < 16) ? wsum[lane] : 0;
#pragma unroll
        for (int off = 1; off < 16; off <<= 1) {
            int t = __shfl_up(y, off, 64);
            if (lane >= off) y += t;
        }
        if (lane < 16) wsum[lane] = y;
    }
    __syncthreads();
    int woff = wid ? wsum[wid - 1] : 0;
    return woff + x - v;
}

__global__ __launch_bounds__(1024) void scan1_kernel(
    const int* __restrict__ cnt_store, int* __restrict__ scanex,
    int* __restrict__ bsum, int total)
{
    int tid = threadIdx.x;
    int i = blockIdx.x * 1024 + tid;
    int v = (i < total) ? cnt_store[i] : 0;
    int excl = block_excl_scan(v, tid);
    if (i < total) scanex[i] = excl;
    if (tid == 1023) bsum[blockIdx.x] = excl + v;
}

__global__ __launch_bounds__(1024) void scan2_kernel(int* __restrict__ bsum, int nb)
{
    int tid = threadIdx.x;
    int v = (tid < nb) ? bsum[tid] : 0;
    int excl = block_excl_scan(v, tid);
    if (tid < nb) bsum[tid] = excl;
}

__global__ __launch_bounds__(256) void scan3_kernel(
    const int* __restrict__ scanex, const int* __restrict__ bsum,
    int* __restrict__ cursor_base, int* __restrict__ bucket_ptr,
    int total, int E)
{
    int i = blockIdx.x * 256 + threadIdx.x;
    if (i >= total) return;
    int v = scanex[i] + bsum[i >> 10];
    int rel = i / (NB * GF);
    int rem = i - rel * (NB * GF);
    int b = rem / GF, rep = rem - b * GF;
    int local = v - rel * E;            // each relation has exactly E edges
    cursor_base[i] = local;
    if (rep == 0) bucket_ptr[rel * (NB + 1) + b] = local;
    if (rem == 0) bucket_ptr[rel * (NB + 1) + NB] = E;
}

// ---- fill4: all relations; coarse bucket sort; LDS cursors -----------------
__global__ __launch_bounds__(512) void fill4_kernel(
    Ptrs p, const int* __restrict__ cursor_base,
    ull* __restrict__ csr8, int E)
{
    __shared__ int lcur[NB];
    const int rel = blockIdx.x / GF;
    const int rep = blockIdx.x - rel * GF;
    const int tid = threadIdx.x;
    const int* cb = cursor_base + (size_t)rel * NB * GF;
    for (int b = tid; b < NB; b += 512)
        lcur[b] = cb[(size_t)b * GF + rep];
    __syncthreads();
    const int es  = (E + GF - 1) / GF;
    const int beg = rep * es;
    const int end = min(beg + es, E);
    const int* src = p.src[rel];
    const int* dst = p.dst[rel];
    const float* w = p.w[rel];
    ull* c8 = csr8 + (size_t)rel * E;
    for (int e = beg + tid; e < end; e += 512) {
        int s = src[e];
        int d = dst[e];
        int pos = atomicAdd(&lcur[d >> 6], 1);
        ull rec = (ull)(unsigned)(s | ((d & 63) << 16)) |
                  ((ull)__float_as_uint(w[e]) << 32);
        c8[pos] = rec;
    }
}

// ---- sort24: all relations; bucket -> exact per-dst CSR; bake wn; 4B recs --
__global__ __launch_bounds__(256) void sort24_kernel(
    const int* __restrict__ bucket_ptr, const ull* __restrict__ csr8,
    const float* __restrict__ rdego, unsigned* __restrict__ csr2u,
    int* __restrict__ row_ptr, int E)
{
    __shared__ int cnt[64];
    __shared__ int cur[64];
    __shared__ float swsum[64];
    const int rel = blockIdx.x / NB;
    const int b   = blockIdx.x - rel * NB;
    const int tid = threadIdx.x;
    const int* bp_r = bucket_ptr + rel * (NB + 1);
    const ull* c8 = csr8 + (size_t)rel * E;
    unsigned* c2 = csr2u + (size_t)rel * E;
    int* rp_r = row_ptr + rel * (NN + 1);
    const float* rd = rdego + (size_t)rel * NN;
    const int beg = bp_r[b];
    const int end = bp_r[b + 1];
    if (tid < 64) { cnt[tid] = 0; swsum[tid] = 0.f; }
    __syncthreads();
    for (int e = beg + tid; e < end; e += 256) {
        ull rec = c8[e];
        int j = (int)((rec >> 16) & 63);
        atomicAdd(&cnt[j], 1);
        atomicAdd(&swsum[j], __uint_as_float((unsigned)(rec >> 32)));
    }
    __syncthreads();
    if (tid < 64) {                      // wave 0: exclusive scan of 64 bins
        int v = cnt[tid];
        int x = v;
#pragma unroll
        for (int off = 1; off < 64; off <<= 1) {
            int y = __shfl_up(x, off, 64);
            if (tid >= off) x += y;
        }
        int start = beg + x - v;
        cur[tid] = start;
        rp_r[b * 64 + tid] = start;
        swsum[tid] = rsqrtf(swsum[tid]);
        if (b == 0 && tid == 0) rp_r[NN] = E;
    }
    __syncthreads();
    for (int e = beg + tid; e < end; e += 256) {
        ull rec = c8[e];
        int j = (int)((rec >> 16) & 63);
        int s = (int)(rec & 0xFFFF);
        float wn = __uint_as_float((unsigned)(rec >> 32)) * rd[s] * swsum[j];
        int pos = atomicAdd(&cur[j], 1);
        c2[pos] = (unsigned)s |
                  ((unsigned)__half_as_ushort(__float2half_rn(wn)) << 16);
    }
}

// ---- gather4: all relations; one wave/node; 4 edges x 16 lanes x 16B -------
__global__ __launch_bounds__(256) void gather4_kernel(
    const int* __restrict__ row_ptr, const unsigned* __restrict__ csr2u,
    const __half* __restrict__ h16com, const __half* __restrict__ h16pos,
    __half* __restrict__ agg16, int gBlocks, int E)
{
    int rel = blockIdx.x / gBlocks;
    int lb  = blockIdx.x - rel * gBlocks;
    int node = (lb * 256 + threadIdx.x) >> 6;
    int lane = threadIdx.x & 63;
    if (node >= NN) return;
    const int* rp = row_ptr + rel * (NN + 1);
    const unsigned* c2 = csr2u + (size_t)rel * E;
    const __half* h16 = (rel == 0 || rel == 3) ? h16com : h16pos;
    __half* agg = agg16 + (size_t)rel * NN * D;

    int beg = rp[node], end = rp[node + 1];
    const int g = lane >> 4, l16 = lane & 15;

    float acc[8] = {};
    for (int e = beg; e < end; e += 4) {
        int ee = e + g;
        int valid = ee < end;
        unsigned rec = __builtin_nontemporal_load(c2 + (valid ? ee : (end - 1)));
        int s = (int)(rec & 0xFFFF);
        float wn = valid ? __half2float(__ushort_as_half((unsigned short)(rec >> 16))) : 0.f;
        f32x4 hv4 = ((const f32x4*)(h16 + (size_t)s * D))[l16];
        __half2* hp = (__half2*)&hv4;
        float2 f0 = __half22float2(hp[0]);
        float2 f1 = __half22float2(hp[1]);
        float2 f2 = __half22float2(hp[2]);
        float2 f3 = __half22float2(hp[3]);
        acc[0] += wn * f0.x; acc[1] += wn * f0.y;
        acc[2] += wn * f1.x; acc[3] += wn * f1.y;
        acc[4] += wn * f2.x; acc[5] += wn * f2.y;
        acc[6] += wn * f3.x; acc[7] += wn * f3.y;
    }
#pragma unroll
    for (int k = 0; k < 8; ++k) {
        acc[k] += __shfl_xor(acc[k], 16, 64);
        acc[k] += __shfl_xor(acc[k], 32, 64);
    }
    if (g == 0) {
        __half2 pack[4];
        pack[0] = __floats2half2_rn(acc[0], acc[1]);
        pack[1] = __floats2half2_rn(acc[2], acc[3]);
        pack[2] = __floats2half2_rn(acc[4], acc[5]);
        pack[3] = __floats2half2_rn(acc[6], acc[7]);
        __builtin_nontemporal_store(*(f32x4*)pack,
                                    (f32x4*)(agg + (size_t)node * D) + l16);
    }
}

// ---- projmf: MFMA fp16 GEMM, both relations of an output half fused --------
// out = 0.5*(relu(aggA@WA + bA) + relu(aggB@WB + bB)); 64 rows/block, 4 waves
__global__ __launch_bounds__(256) void projmf_kernel(
    const __half* __restrict__ aggA, const __half* __restrict__ wpA,
    const float* __restrict__ bA,
    const __half* __restrict__ aggB, const __half* __restrict__ wpB,
    const float* __restrict__ bB, float* __restrict__ outh)
{
    __shared__ char As[2][64 * 256];    // 2 x 16 KB, XOR-swizzled rows
    const int t = threadIdx.x;
    const int row0 = blockIdx.x * 64;

    for (int r2 = 0; r2 < 2; ++r2) {
        const float4* src = (const float4*)((r2 ? aggB : aggA) + (size_t)row0 * D);
        for (int i = t; i < 1024; i += 256) {
            int row = i >> 4, ch = i & 15;
            int byte = row * 256 + ch * 16;
            byte ^= (row & 7) << 4;
            *(float4*)(As[r2] + byte) = src[i];
        }
    }
    __syncthreads();

    const int wv = t >> 6, lane = t & 63;
    const int rbase = wv * 16;

    f16x8 aA[4], aB[4];
#pragma unroll
    for (int kt = 0; kt < 4; ++kt) {
        int row = rbase + (lane & 15);
        int byte = row * 256 + kt * 64 + (lane >> 4) * 16;
        byte ^= (row & 7) << 4;
        aA[kt] = *(const f16x8*)(As[0] + byte);
        aB[kt] = *(const f16x8*)(As[1] + byte);
    }

    f32x4 accA[8], accB[8];
#pragma unroll
    for (int i = 0; i < 8; ++i) {
        accA[i] = (f32x4){0.f, 0.f, 0.f, 0.f};
        accB[i] = (f32x4){0.f, 0.f, 0.f, 0.f};
    }

#pragma unroll
    for (int ct = 0; ct < 8; ++ct) {
#pragma unroll
        for (int kt = 0; kt < 4; ++kt) {
            f16x8 bfA = *(const f16x8*)(wpA + ((size_t)((kt * 8 + ct) * 64 + lane)) * 8);
            f16x8 bfB = *(const f16x8*)(wpB + ((size_t)((kt * 8 + ct) * 64 + lane)) * 8);
            accA[ct] = __builtin_amdgcn_mfma_f32_16x16x32_f16(aA[kt], bfA, accA[ct], 0, 0, 0);
            accB[ct] = __builtin_amdgcn_mfma_f32_16x16x32_f16(aB[kt], bfB, accB[ct], 0, 0, 0);
        }
    }

    // C/D layout: col = lane&15, row = (lane>>4)*4 + v   [dtype-independent]
#pragma unroll
    for (int ct = 0; ct < 8; ++ct) {
        int col = ct * 16 + (lane & 15);
        float ba = bA[col], bb = bB[col];
#pragma unroll
        for (int v = 0; v < 4; ++v) {
            int row = row0 + rbase + (lane >> 4) * 4 + v;
            float r = 0.5f * (fmaxf(accA[ct][v] + ba, 0.f) +
                              fmaxf(accB[ct][v] + bb, 0.f));
            outh[(size_t)row * D + col] = r;
        }
    }
}

extern "C" void kernel_launch(void* const* d_in, const int* in_sizes, int n_in,
                              void* d_out, int out_size, void* d_ws, size_t ws_size,
                              hipStream_t stream) {
    const float* com_emb = (const float*)d_in[0];
    const float* pos_emb = (const float*)d_in[1];
    const int E = in_sizes[2];       // 1,000,000
    const int N = NN;

    float* out = (float*)d_out;
    float* out_com = out;
    float* out_pos = out + (size_t)N * D;

    // relation order: 0=cflow(com->com) 1=supply(pos->com) 2=pflow(pos->pos) 3=demand(com->pos)
    Ptrs ptrs;
    ptrs.src[0] = (const int*)d_in[8];  ptrs.dst[0] = (const int*)d_in[9];  ptrs.w[0] = (const float*)d_in[10];
    ptrs.src[1] = (const int*)d_in[5];  ptrs.dst[1] = (const int*)d_in[6];  ptrs.w[1] = (const float*)d_in[7];
    ptrs.src[2] = (const int*)d_in[11]; ptrs.dst[2] = (const int*)d_in[12]; ptrs.w[2] = (const float*)d_in[13];
    ptrs.src[3] = (const int*)d_in[2];  ptrs.dst[3] = (const int*)d_in[3];  ptrs.w[3] = (const float*)d_in[4];

    // ws layout (~125 MB of the 256 MB workspace; no overlays)
    const int totalCnt = 4 * NB * GF;           // 320000
    char* p = (char*)d_ws;
    float* rdego       = (float*)p;  p += (size_t)4 * N * 4;
    int*   cnt_store   = (int*)p;    p += (size_t)totalCnt * 4;
    int*   scanex      = (int*)p;    p += (size_t)totalCnt * 4;
    int*   bsum        = (int*)p;    p += (size_t)1024 * 4;
    int*   cursor_base = (int*)p;    p += (size_t)totalCnt * 4;
    int*   bucket_ptr  = (int*)p;    p += (size_t)4 * (NB + 1) * 4;
    int*   row_ptr     = (int*)p;    p += (size_t)4 * (N + 1) * 4;
    ull*   csr8        = (ull*)p;    p += (size_t)4 * E * 8;               // 32 MB
    unsigned* csr2u    = (unsigned*)p; p += (size_t)4 * E * 4;             // 16 MB
    __half* h16com     = (__half*)p; p += (size_t)N * D * 2;               // 10.24 MB
    __half* h16pos     = (__half*)p; p += (size_t)N * D * 2;               // 10.24 MB
    __half* agg16      = (__half*)p; p += (size_t)4 * N * D * 2;           // 40.96 MB
    __half* wpack      = (__half*)p; p += (size_t)4 * 2048 * 8 * 2;        // 128 KB
    __half* histo16    = (__half*)p;                                       // 20.48 MB

    const int cBlocks = (N * D / 8 + 255) / 256;
    const int gBlocks = N / 4;                 // 1 wave per dst node
    const int sBlocks = (totalCnt + 1023) / 1024;

    conv_kernel<<<cBlocks, 256, 0, stream>>>(com_emb, h16com, N * D / 8);
    conv_kernel<<<cBlocks, 256, 0, stream>>>(pos_emb, h16pos, N * D / 8);
    wpack_kernel<<<32, 256, 0, stream>>>((const float*)d_in[18], (const float*)d_in[16],
                                         (const float*)d_in[20], (const float*)d_in[14],
                                         wpack);

    hist_kernel<<<4 * GH, 1024, 0, stream>>>(ptrs, histo16, E);
    reduce_kernel<<<(4 * N + 255) / 256, 256, 0, stream>>>(histo16, rdego, 4 * N);
    bcnt_kernel<<<4 * GF, 256, 0, stream>>>(ptrs, cnt_store, E);
    scan1_kernel<<<sBlocks, 1024, 0, stream>>>(cnt_store, scanex, bsum, totalCnt);
    scan2_kernel<<<1, 1024, 0, stream>>>(bsum, sBlocks);
    scan3_kernel<<<(totalCnt + 255) / 256, 256, 0, stream>>>(scanex, bsum, cursor_base,
                                                             bucket_ptr, totalCnt, E);

    fill4_kernel<<<4 * GF, 512, 0, stream>>>(ptrs, cursor_base, csr8, E);
    sort24_kernel<<<4 * NB, 256, 0, stream>>>(bucket_ptr, csr8, rdego, csr2u, row_ptr, E);
    gather4_kernel<<<4 * gBlocks, 256, 0, stream>>>(row_ptr, csr2u, h16com, h16pos,
                                                    agg16, gBlocks, E);

    // com half: A=supply(rel1), B=cflow(rel0); pos half: A=demand(rel3), B=pflow(rel2)
    projmf_kernel<<<N / 64, 256, 0, stream>>>(
        agg16 + (size_t)1 * N * D, wpack + (size_t)1 * 16384, (const float*)d_in[17],
        agg16 + (size_t)0 * N * D, wpack + (size_t)0 * 16384, (const float*)d_in[19],
        out_com);
    projmf_kernel<<<N / 64, 256, 0, stream>>>(
        agg16 + (size_t)3 * N * D, wpack + (size_t)3 * 16384, (const float*)d_in[15],
        agg16 + (size_t)2 * N * D, wpack + (size_t)2 * 16384, (const float*)d_in[21],
        out_pos);
}